// Round 8
// baseline (214.878 us; speedup 1.0000x reference)
//
#include <hip/hip_runtime.h>
#include <math.h>

#define PP   7
#define NDIR 49
#define CIN  3
#define KK   147      // CIN * 49
#define KPAD 160      // bf16 weight row stride: 5 k-steps of 32, zero-padded tail
#define EE   384
#define HH   224
#define WW   224
#define GG   16       // patches per block
#define TB   256
#define NPX  112      // GG*PP pixel columns per block strip
#define WSTR 208      // packed metric-weight row stride (floats), 16B-aligned rows
#define SROW 164      // samp row stride (floats): 147 data + zero pad, 16B-aligned
#define WREG 784      // per-wave LDS region (floats): strip 196 quads / samp 4x164
#define SSTR 17       // legacy samp stride (planar fallback kernel only)

typedef __attribute__((ext_vector_type(8))) __bf16 bf16x8;
typedef __attribute__((ext_vector_type(4))) float  f32x4;

__device__ __forceinline__ float sigmoidf_(float v) {
    return 1.0f / (1.0f + expf(-v));
}

// ---- K0: fused pack.
// (a) proj_w (E,K) fp32 -> bf16 [E][KPAD];
// (b) x NCHW -> NHW4 fp32 (channel-interleaved float4) — r3 A/B: worth ~43 us
//     in the gather for ~16 us streaming cost;
// (c) metric_w -> mwg[prm][(i*7+j)*4 + c]: conv reads weight quads as 16B loads.
__global__ void pack_kernel(const float* __restrict__ x,
                            const float* __restrict__ pw,
                            const float* __restrict__ mw,
                            float* __restrict__ xp,
                            unsigned short* __restrict__ pwB,
                            float* __restrict__ mwg,
                            int npix4) {
    int idx = blockIdx.x * blockDim.x + threadIdx.x;
    if (idx < EE * KPAD) {
        int e = idx / KPAD;
        int k = idx - e * KPAD;
        float v = (k < KK) ? pw[e * KK + k] : 0.0f;
        __bf16 h = (__bf16)v;
        pwB[idx] = *(unsigned short*)&h;
    }
    if (idx < 7 * WSTR) {
        int prm = idx / WSTR, r = idx - prm * WSTR;
        float v = 0.0f;
        if (r < 196) {
            int q = r >> 2, c = r & 3;        // q = i*7+j in 0..48
            if (c < 3) v = mw[prm * KK + c * 49 + q];
        }
        mwg[idx] = v;
    }
    if (idx < npix4) {
        const int ppi = HH * WW / 4;
        int b = idx / ppi;
        int p = (idx - b * ppi) * 4;
        const float* xb = x + (size_t)b * (CIN * HH * WW) + p;
        f32x4 r0 = *(const f32x4*)(xb);
        f32x4 r1 = *(const f32x4*)(xb + HH * WW);
        f32x4 r2 = *(const f32x4*)(xb + 2 * HH * WW);
        float* op = xp + ((size_t)b * (HH * WW) + p) * 4;
        #pragma unroll
        for (int i = 0; i < 4; ++i) {
            f32x4 v = {r0[i], r1[i], r2[i], 0.0f};
            *(f32x4*)(op + i * 4) = v;
        }
    }
}

// ---- K1: WAVE-AUTONOMOUS fused kernel. r6 lesson: with 4 barriers the block
// is phase-serialization bound (all pipes <30% busy, duration pinned at ~72us
// across wildly different instruction mixes). Here each wave owns 4 patches
// end-to-end with ZERO block synchronization — stage/conv/derive/gather are
// wave-private (LDS region per wave, program-order safe within a wave) — then
// ONE __syncthreads() before the block-wide MFMA GEMM. Waves drift through
// phases independently, overlapping conv VALU with gather loads across waves.
__launch_bounds__(TB, 8)
__global__ void fused_kernel(const float* __restrict__ xp,   // packed NHW4
                             const float* __restrict__ mwg,  // packed metric w
                             const float* __restrict__ mb,
                             const unsigned short* __restrict__ pwB,
                             const float* __restrict__ pb,
                             float* __restrict__ out) {
    __shared__ float par_s[GG][8];                  //  512 B
    __shared__ float der_s[GG][5];                  //  320 B
    // per-wave region: phase A strip = 196 quads (784 fl); phase B samp rows
    // [4][SROW=164] = 656 fl (union — strip dead after conv, same wave).
    __shared__ __align__(16) float buf[4 * WREG];   // 12544 B; total ~13.4 KB

    const int t    = threadIdx.x;
    const int lane = t & 63;
    const int wv   = t >> 6;            // wave owns patches 4wv..4wv+3
    const int blk  = blockIdx.x;
    const int b    = blk >> 6;
    const int rem  = blk & 63;
    const int hp   = rem >> 1;
    const int wp0  = (rem & 1) * GG;
    const size_t m0 = (size_t)blk * GG;
    const int row0 = hp * PP;
    const int col0 = wp0 * PP;
    const int wbase = wv * WREG;

    const size_t pbase = (size_t)b * (HH * WW);

    // ---- stage: wave loads its 4 patches' 7x28 pixel-quad strip (coalesced)
    const int colw = col0 + wv * 28;    // quad-column base of this wave's strip
    #pragma unroll
    for (int r = 0; r < 4; ++r) {
        int idx = r * 64 + lane;
        if (idx < 196) {
            int i = idx / 28, j28 = idx - i * 28;
            f32x4 v = *(const f32x4*)(xp + (pbase + (size_t)(row0 + i) * WW + colw + j28) * 4);
            *(f32x4*)&buf[wbase + idx * 4] = v;     // strip[i][j28][c]
        }
    }

    // ---- conv: 28 dots (7 prm x 4 patches) x 2-lane split-K. Weights straight
    // from global mwg (5.8 KB, L1-hot across all blocks). Even/odd tap split,
    // butterfly combine.
    if (lane < 56) {
        int d = lane >> 1, h = lane & 1;
        int prm = d >> 2, gl = d & 3;
        const float* wq = mwg + prm * WSTR;
        const float* pq = &buf[wbase + gl * 28];    // + (i*28 + j)*4 floats
        float a0 = 0.0f, a1 = 0.0f, a2 = 0.0f;
        #pragma unroll 5
        for (int it = 0; it < 25; ++it) {
            int q = it * 2 + h;
            if (q < 49) {
                int i = q / 7, j = q - i * 7;       // const-div: mul_hi+shift
                f32x4 pix = *(const f32x4*)&pq[i * 112 + j * 4];
                f32x4 w4  = *(const f32x4*)&wq[q * 4];
                a0 = fmaf(pix[0], w4[0], a0);
                a1 = fmaf(pix[1], w4[1], a1);
                a2 = fmaf(pix[2], w4[2], a2);
            }
        }
        float a = a0 + a1 + a2;
        a += __shfl_xor(a, 1);
        par_s[wv * 4 + gl][prm] = a;                // both halves write same value
    }

    // ---- derive: 4 lanes, one patch each (wave-private; lgkmcnt ordering only)
    if (lane < 4) {
        int g = wv * 4 + lane;
        float a0 = par_s[g][0] + mb[0], a1 = par_s[g][1] + mb[1];
        float a2 = par_s[g][2] + mb[2], a3 = par_s[g][3] + mb[3];
        float a4 = par_s[g][4] + mb[4], a5 = par_s[g][5] + mb[5];
        float a6 = par_s[g][6] + mb[6];
        float nrm = sqrtf(a0 * a0 + a1 * a1);
        float inv = 1.0f / fmaxf(nrm, 1e-12f);
        float v0 = a0 * inv, v1 = a1 * inv;
        float e0 = 2.0f * sigmoidf_(a2);
        float e1 = 2.0f * sigmoidf_(a3);
        float sc = 0.5f + 1.5f * sigmoidf_(a4);
        e0 *= sc; e1 *= sc;
        float wn  = sqrtf(a5 * a5 + a6 * a6);
        float wsc = 0.5f * sigmoidf_(wn);
        der_s[g][0] = e0 * v0 * v0 + e1 * v1 * v1;
        der_s[g][1] = (e0 - e1) * v0 * v1;
        der_s[g][2] = e0 * v1 * v1 + e1 * v0 * v0;
        der_s[g][3] = a5 * wsc;
        der_s[g][4] = a6 * wsc;
    }

    // ---- samp tail zero-fill (k=147..163 per row; strip dead after conv)
    for (int z = lane; z < 4 * (SROW - KK); z += 64) {
        int rw = z / (SROW - KK), kk = z - rw * (SROW - KK);
        buf[wbase + rw * SROW + KK + kk] = 0.0f;
    }

    // ---- gather: wave's 196 items (4 patches x 49 dirs), per-item trig
    // (no dirs table -> no cross-wave dependency), proven r2 geometry.
    #pragma unroll
    for (int r = 0; r < 4; ++r) {
        int idx = r * 64 + lane;
        if (idx < 196) {
            int gl = idx / 49, n = idx - gl * 49;
            int g  = wv * 4 + gl;
            float bs, st, sv;
            if (n >= 25)     { bs = 25.0f; st = 0.26179938779914941f; sv = 1.0f; }
            else if (n >= 9) { bs = 9.0f;  st = 0.39269908169872414f; sv = 0.66666669f; }
            else if (n >= 1) { bs = 1.0f;  st = 0.78539816339744831f; sv = 0.33333334f; }
            else             { bs = 0.0f;  st = 0.0f;                 sv = 0.0f; }
            float th = ((float)n - bs) * st;
            float u0 = __cosf(th), u1 = __sinf(th);
            float M00 = der_s[g][0], M01 = der_s[g][1], M11 = der_s[g][2];
            float w0 = der_s[g][3], w1 = der_s[g][4];
            float quad  = u0 * u0 * M00 + 2.0f * u0 * u1 * M01 + u1 * u1 * M11;
            float drift = w0 * u0 + w1 * u1;
            float F = sqrtf(quad + 1e-6f) + drift;
            float rr = sv / (F + 1e-6f);
            float py = (float)(row0 + 3) + u1 * rr;
            float px = (float)(col0 + g * PP + 3) + u0 * rr;
            float y0f = floorf(py), x0f = floorf(px);
            float y1f = y0f + 1.0f, x1f = x0f + 1.0f;
            float wy = py - y0f, wx = px - x0f;
            float c00 = (1.0f - wy) * (1.0f - wx);
            float c01 = (1.0f - wy) * wx;
            float c10 = wy * (1.0f - wx);
            float c11 = wy * wx;
            bool vy0 = (y0f >= 0.0f) && (y0f <= (float)(HH - 1));
            bool vy1 = (y1f >= 0.0f) && (y1f <= (float)(HH - 1));
            bool vx0 = (x0f >= 0.0f) && (x0f <= (float)(WW - 1));
            bool vx1 = (x1f >= 0.0f) && (x1f <= (float)(WW - 1));
            c00 *= (vy0 && vx0) ? 1.0f : 0.0f;
            c01 *= (vy0 && vx1) ? 1.0f : 0.0f;
            c10 *= (vy1 && vx0) ? 1.0f : 0.0f;
            c11 *= (vy1 && vx1) ? 1.0f : 0.0f;
            int iy0 = (int)fminf(fmaxf(y0f, 0.0f), (float)(HH - 1));
            int iy1 = (int)fminf(fmaxf(y1f, 0.0f), (float)(HH - 1));
            int ix0 = (int)fminf(fmaxf(x0f, 0.0f), (float)(WW - 1));
            int ix1 = (int)fminf(fmaxf(x1f, 0.0f), (float)(WW - 1));
            f32x4 q00 = *(const f32x4*)(xp + (pbase + (size_t)(iy0 * WW + ix0)) * 4);
            f32x4 q01 = *(const f32x4*)(xp + (pbase + (size_t)(iy0 * WW + ix1)) * 4);
            f32x4 q10 = *(const f32x4*)(xp + (pbase + (size_t)(iy1 * WW + ix0)) * 4);
            f32x4 q11 = *(const f32x4*)(xp + (pbase + (size_t)(iy1 * WW + ix1)) * 4);
            #pragma unroll
            for (int c = 0; c < CIN; ++c) {
                buf[wbase + gl * SROW + c * NDIR + n] =
                    q00[c] * c00 + q01[c] * c01 + q10[c] * c10 + q11[c] * c11;
            }
        }
    }

    __syncthreads();   // the ONLY barrier: samp complete, GEMM reads all rows

    // ---- MFMA projection GEMM (r3/r6 verified, operand-swapped): A = pw rows
    // (M=e), B = samp (N=m). Lane owns 4 consecutive e of one output row.
    const int nrow = lane & 15;
    const int hi   = lane >> 4;

    bf16x8 sfr[5];
    const float* srow = &buf[(nrow >> 2) * WREG + (nrow & 3) * SROW];
    #pragma unroll
    for (int ks = 0; ks < 5; ++ks) {
        f32x4 lo = *(const f32x4*)&srow[ks * 32 + hi * 8];
        f32x4 hv = *(const f32x4*)&srow[ks * 32 + hi * 8 + 4];
        #pragma unroll
        for (int j = 0; j < 4; ++j) sfr[ks][j] = (__bf16)lo[j];
        #pragma unroll
        for (int j = 0; j < 4; ++j) sfr[ks][4 + j] = (__bf16)hv[j];
    }

    float* orow = out + (m0 + nrow) * EE;
    #pragma unroll
    for (int q = 0; q < 6; ++q) {
        int tile = wv * 6 + q;
        int erow = tile * 16 + nrow;
        const unsigned short* arow = pwB + (size_t)erow * KPAD + hi * 8;
        f32x4 acc = {0.0f, 0.0f, 0.0f, 0.0f};
        #pragma unroll
        for (int ks = 0; ks < 5; ++ks) {
            bf16x8 afr = *(const bf16x8*)&arow[ks * 32];
            acc = __builtin_amdgcn_mfma_f32_16x16x32_bf16(afr, sfr[ks], acc, 0, 0, 0);
        }
        int e0 = tile * 16 + hi * 4;
        f32x4 b4 = *(const f32x4*)&pb[e0];
        f32x4 o = acc + b4;
        *(f32x4*)&orow[e0] = o;
    }
}

// ---- planar fallback (only if workspace can't hold the packed image)
__launch_bounds__(TB, 6)
__global__ void fused_planar_kernel(const float* __restrict__ x,
                                    const float* __restrict__ mw,
                                    const float* __restrict__ mb,
                                    const unsigned short* __restrict__ pwB,
                                    const float* __restrict__ pb,
                                    float* __restrict__ out) {
    __shared__ float mws[7 * KK];
    __shared__ float dirs[NDIR][3];
    __shared__ float par_s[GG][8];
    __shared__ float der_s[GG][5];
    __shared__ __align__(16) float buf[2512];

    const int t   = threadIdx.x;
    const int blk = blockIdx.x;
    const int b   = blk >> 6;
    const int rem = blk & 63;
    const int hp  = rem >> 1;
    const int wp0 = (rem & 1) * GG;
    const size_t m0 = (size_t)blk * GG;
    const int row0 = hp * PP;
    const int col0 = wp0 * PP;
    const float* xb = x + (size_t)b * (CIN * HH * WW);

    for (int i = t; i < 7 * KK; i += TB) mws[i] = mw[i];
    if (t >= 64 && t < 64 + NDIR) {
        int n = t - 64;
        float u0, u1, s;
        if (n == 0)      { u0 = 1.0f; u1 = 0.0f; s = 0.0f; }
        else if (n < 9)  { float th = (float)(n - 1)  * 0.78539816339744831f; u0 = cosf(th); u1 = sinf(th); s = 0.33333334f; }
        else if (n < 25) { float th = (float)(n - 9)  * 0.39269908169872414f; u0 = cosf(th); u1 = sinf(th); s = 0.66666669f; }
        else             { float th = (float)(n - 25) * 0.26179938779914941f; u0 = cosf(th); u1 = sinf(th); s = 1.0f; }
        dirs[n][0] = u0; dirs[n][1] = u1; dirs[n][2] = s;
    }
    for (int item = t; item < CIN * 7 * NPX; item += TB) {
        int c = item / (7 * NPX), r2 = item - c * (7 * NPX);
        int i = r2 / NPX, px = r2 - i * NPX;
        buf[item] = xb[(size_t)c * (HH * WW) + (size_t)(row0 + i) * WW + col0 + px];
    }
    __syncthreads();
    if (t < 112) {
        int prm = t >> 4, g = t & 15;
        const float* wrow = &mws[prm * KK];
        float acc0 = 0.0f, acc1 = 0.0f, acc2 = 0.0f;
        #pragma unroll 1
        for (int i = 0; i < 7; ++i) {
            const float* b0 = &buf[(0 * 7 + i) * NPX + g * 7];
            const float* b1 = &buf[(1 * 7 + i) * NPX + g * 7];
            const float* b2 = &buf[(2 * 7 + i) * NPX + g * 7];
            #pragma unroll
            for (int j = 0; j < 7; ++j) {
                acc0 = fmaf(b0[j], wrow[i * 7 + j], acc0);
                acc1 = fmaf(b1[j], wrow[49 + i * 7 + j], acc1);
                acc2 = fmaf(b2[j], wrow[98 + i * 7 + j], acc2);
            }
        }
        par_s[g][prm] = mb[prm] + acc0 + acc1 + acc2;
    }
    __syncthreads();
    if (t < GG) {
        float a0 = par_s[t][0], a1 = par_s[t][1], a2 = par_s[t][2], a3 = par_s[t][3];
        float a4 = par_s[t][4], a5 = par_s[t][5], a6 = par_s[t][6];
        float nrm = sqrtf(a0 * a0 + a1 * a1);
        float inv = 1.0f / fmaxf(nrm, 1e-12f);
        float v0 = a0 * inv, v1 = a1 * inv;
        float e0 = 2.0f * sigmoidf_(a2);
        float e1 = 2.0f * sigmoidf_(a3);
        float sc = 0.5f + 1.5f * sigmoidf_(a4);
        e0 *= sc; e1 *= sc;
        float wn  = sqrtf(a5 * a5 + a6 * a6);
        float wsc = 0.5f * sigmoidf_(wn);
        der_s[t][0] = e0 * v0 * v0 + e1 * v1 * v1;
        der_s[t][1] = (e0 - e1) * v0 * v1;
        der_s[t][2] = e0 * v1 * v1 + e1 * v0 * v0;
        der_s[t][3] = a5 * wsc;
        der_s[t][4] = a6 * wsc;
    }
    __syncthreads();
    for (int item = t; item < GG * NDIR; item += TB) {
        int g = item / NDIR;
        int n = item - g * NDIR;
        float u0 = dirs[n][0], u1 = dirs[n][1], s = dirs[n][2];
        float M00 = der_s[g][0], M01 = der_s[g][1], M11 = der_s[g][2];
        float w0 = der_s[g][3], w1 = der_s[g][4];
        float quad  = u0 * u0 * M00 + 2.0f * u0 * u1 * M01 + u1 * u1 * M11;
        float drift = w0 * u0 + w1 * u1;
        float F = sqrtf(quad + 1e-6f) + drift;
        float r = s / (F + 1e-6f);
        float py = (float)(row0 + 3) + u1 * r;
        float px = (float)(col0 + g * PP + 3) + u0 * r;
        float y0f = floorf(py), x0f = floorf(px);
        float y1f = y0f + 1.0f, x1f = x0f + 1.0f;
        float wy = py - y0f, wx = px - x0f;
        float c00 = (1.0f - wy) * (1.0f - wx);
        float c01 = (1.0f - wy) * wx;
        float c10 = wy * (1.0f - wx);
        float c11 = wy * wx;
        bool vy0 = (y0f >= 0.0f) && (y0f <= (float)(HH - 1));
        bool vy1 = (y1f >= 0.0f) && (y1f <= (float)(HH - 1));
        bool vx0 = (x0f >= 0.0f) && (x0f <= (float)(WW - 1));
        bool vx1 = (x1f >= 0.0f) && (x1f <= (float)(WW - 1));
        c00 *= (vy0 && vx0) ? 1.0f : 0.0f;
        c01 *= (vy0 && vx1) ? 1.0f : 0.0f;
        c10 *= (vy1 && vx0) ? 1.0f : 0.0f;
        c11 *= (vy1 && vx1) ? 1.0f : 0.0f;
        int iy0 = (int)fminf(fmaxf(y0f, 0.0f), (float)(HH - 1));
        int iy1 = (int)fminf(fmaxf(y1f, 0.0f), (float)(HH - 1));
        int ix0 = (int)fminf(fmaxf(x0f, 0.0f), (float)(WW - 1));
        int ix1 = (int)fminf(fmaxf(x1f, 0.0f), (float)(WW - 1));
        int o00 = iy0 * WW + ix0, o01 = iy0 * WW + ix1;
        int o10 = iy1 * WW + ix0, o11 = iy1 * WW + ix1;
        #pragma unroll
        for (int c = 0; c < CIN; ++c) {
            const float* xc = xb + c * (HH * WW);
            buf[(c * NDIR + n) * SSTR + g] =
                xc[o00] * c00 + xc[o01] * c01 + xc[o10] * c10 + xc[o11] * c11;
        }
    }
    __syncthreads();
    const int lane = t & 63;
    const int wv   = t >> 6;
    const int nrow = lane & 15;
    const int hi   = lane >> 4;
    bf16x8 sfr[5];
    #pragma unroll
    for (int ks = 0; ks < 5; ++ks) {
        #pragma unroll
        for (int j = 0; j < 8; ++j) {
            int k = ks * 32 + hi * 8 + j;
            float v = (k < KK) ? buf[k * SSTR + nrow] : 0.0f;
            sfr[ks][j] = (__bf16)v;
        }
    }
    float* orow = out + (m0 + nrow) * EE;
    #pragma unroll
    for (int q = 0; q < 6; ++q) {
        int tile = wv * 6 + q;
        int erow = tile * 16 + nrow;
        const unsigned short* arow = pwB + (size_t)erow * KPAD + hi * 8;
        f32x4 acc = {0.0f, 0.0f, 0.0f, 0.0f};
        #pragma unroll
        for (int ks = 0; ks < 5; ++ks) {
            bf16x8 afr = *(const bf16x8*)&arow[ks * 32];
            acc = __builtin_amdgcn_mfma_f32_16x16x32_bf16(afr, sfr[ks], acc, 0, 0, 0);
        }
        int e0 = tile * 16 + hi * 4;
        f32x4 b4 = *(const f32x4*)&pb[e0];
        f32x4 o = acc + b4;
        *(f32x4*)&orow[e0] = o;
    }
}

extern "C" void kernel_launch(void* const* d_in, const int* in_sizes, int n_in,
                              void* d_out, int out_size, void* d_ws, size_t ws_size,
                              hipStream_t stream) {
    const float* x  = (const float*)d_in[0];
    const float* mw = (const float*)d_in[1];
    const float* mb = (const float*)d_in[2];
    const float* pw = (const float*)d_in[3];
    const float* pb = (const float*)d_in[4];
    float* out = (float*)d_out;

    // workspace: [0,120K) pwB | [120K,~126K) mwg | [128K, ...) packed image
    unsigned short* pwB = (unsigned short*)d_ws;
    float* mwg = (float*)((char*)d_ws + (size_t)(EE * KPAD) * 2);
    float* xp  = (float*)((char*)d_ws + (size_t)(1 << 17));

    const int B = in_sizes[0] / (CIN * HH * WW);   // 64
    const int npix = B * HH * WW;
    const int npix4 = npix / 4;
    const size_t need = (size_t)(1 << 17) + (size_t)npix * 4 * sizeof(float);
    const bool packed = ws_size >= need;

    if (packed) {
        int grid = (npix4 > EE * KPAD ? npix4 : EE * KPAD);
        pack_kernel<<<(grid + 255) / 256, 256, 0, stream>>>(x, pw, mw, xp, pwB, mwg, npix4);
        fused_kernel<<<B * 64, TB, 0, stream>>>(xp, mwg, mb, pwB, pb, out);
    } else {
        pack_kernel<<<(EE * KPAD + 255) / 256, 256, 0, stream>>>(x, pw, mw, xp, pwB, mwg, 0);
        fused_planar_kernel<<<B * 64, TB, 0, stream>>>(x, mw, mb, pwB, pb, out);
    }
}

// Round 9
// 210.540 us; speedup vs baseline: 1.0206x; 1.0206x over previous
//
#include <hip/hip_runtime.h>
#include <math.h>

#define PP   7
#define NDIR 49
#define CIN  3
#define KK   147      // CIN * 49
#define KPAD 160      // bf16 weight row stride: 5 k-steps of 32, zero-padded tail
#define EE   384
#define HH   224
#define WW   224
#define GG   16       // patches per block
#define TB   256
#define SSTR 17       // samp LDS row stride (+1 pad: conflict-free GEMM reads)
#define NPX  112      // GG*PP pixel columns per block strip

typedef __attribute__((ext_vector_type(8))) __bf16 bf16x8;
typedef __attribute__((ext_vector_type(4))) float  f32x4;

__device__ __forceinline__ float sigmoidf_(float v) {
    return 1.0f / (1.0f + expf(-v));
}

// ---- K0: fused pack (r2-proven): (a) proj_w -> bf16 [E][KPAD]; (b) x NCHW ->
// NHW4 fp32 (channel-interleaved float4). r3 A/B: packed image worth ~43 us in
// the gather for ~16 us streaming cost here.
__global__ void pack_kernel(const float* __restrict__ x,
                            const float* __restrict__ pw,
                            float* __restrict__ xp,
                            unsigned short* __restrict__ pwB,
                            int npix4) {
    int idx = blockIdx.x * blockDim.x + threadIdx.x;
    if (idx < EE * KPAD) {
        int e = idx / KPAD;
        int k = idx - e * KPAD;
        float v = (k < KK) ? pw[e * KK + k] : 0.0f;
        __bf16 h = (__bf16)v;
        pwB[idx] = *(unsigned short*)&h;
    }
    if (idx < npix4) {
        const int ppi = HH * WW / 4;
        int b = idx / ppi;
        int p = (idx - b * ppi) * 4;
        const float* xb = x + (size_t)b * (CIN * HH * WW) + p;
        f32x4 r0 = *(const f32x4*)(xb);
        f32x4 r1 = *(const f32x4*)(xb + HH * WW);
        f32x4 r2 = *(const f32x4*)(xb + 2 * HH * WW);
        float* op = xp + ((size_t)b * (HH * WW) + p) * 4;
        #pragma unroll
        for (int i = 0; i < 4; ++i) {
            f32x4 v = {r0[i], r1[i], r2[i], 0.0f};
            *(f32x4*)(op + i * 4) = v;
        }
    }
}

// per-item gather geometry (r2-proven math): item -> corner offsets + masked coefs
struct GInfo {
    int g, n;
    int o00, o01, o10, o11;
    float c00, c01, c10, c11;
};

__device__ __forceinline__ GInfo geom_(int item, int row0, int col0,
                                       const float dirs[NDIR][3],
                                       const float der[GG][5]) {
    GInfo r;
    r.g = item / NDIR;
    r.n = item - r.g * NDIR;
    float u0 = dirs[r.n][0], u1 = dirs[r.n][1], s = dirs[r.n][2];
    float M00 = der[r.g][0], M01 = der[r.g][1], M11 = der[r.g][2];
    float w0 = der[r.g][3], w1 = der[r.g][4];
    float quad  = u0 * u0 * M00 + 2.0f * u0 * u1 * M01 + u1 * u1 * M11;
    float drift = w0 * u0 + w1 * u1;
    float F = sqrtf(quad + 1e-6f) + drift;
    float rr = s / (F + 1e-6f);
    float py = (float)(row0 + 3) + u1 * rr;
    float px = (float)(col0 + r.g * PP + 3) + u0 * rr;
    float y0f = floorf(py), x0f = floorf(px);
    float y1f = y0f + 1.0f, x1f = x0f + 1.0f;
    float wy = py - y0f, wx = px - x0f;
    r.c00 = (1.0f - wy) * (1.0f - wx);
    r.c01 = (1.0f - wy) * wx;
    r.c10 = wy * (1.0f - wx);
    r.c11 = wy * wx;
    bool vy0 = (y0f >= 0.0f) && (y0f <= (float)(HH - 1));
    bool vy1 = (y1f >= 0.0f) && (y1f <= (float)(HH - 1));
    bool vx0 = (x0f >= 0.0f) && (x0f <= (float)(WW - 1));
    bool vx1 = (x1f >= 0.0f) && (x1f <= (float)(WW - 1));
    r.c00 *= (vy0 && vx0) ? 1.0f : 0.0f;
    r.c01 *= (vy0 && vx1) ? 1.0f : 0.0f;
    r.c10 *= (vy1 && vx0) ? 1.0f : 0.0f;
    r.c11 *= (vy1 && vx1) ? 1.0f : 0.0f;
    int iy0 = (int)fminf(fmaxf(y0f, 0.0f), (float)(HH - 1));
    int iy1 = (int)fminf(fmaxf(y1f, 0.0f), (float)(HH - 1));
    int ix0 = (int)fminf(fmaxf(x0f, 0.0f), (float)(WW - 1));
    int ix1 = (int)fminf(fmaxf(x1f, 0.0f), (float)(WW - 1));
    r.o00 = iy0 * WW + ix0; r.o01 = iy0 * WW + ix1;
    r.o10 = iy1 * WW + ix0; r.o11 = iy1 * WW + ix1;
    return r;
}

// ---- K1: r2's proven 4-barrier structure (71.1 us — best measured; r6/r8
// structural deviations all lost) + ONE change: the gather is pair-batched with
// __builtin_amdgcn_sched_barrier(0) pinning 8 loads in flight before any interp
// consumes them (r4 lesson: without the sched fence the compiler sinks the
// loads and MLP stays 1x; rule #18/T14). (256,6): VGPR cap ~84 so the 8-quad
// batch fits without spill; measured residency was ~23 waves at either bound.
template<bool PACKED>
__launch_bounds__(TB, 6)
__global__ void fused_kernel(const float* __restrict__ x,    // planar (fallback)
                             const float* __restrict__ xp,   // packed NHW4 (main)
                             const float* __restrict__ mw,
                             const float* __restrict__ mb,
                             const unsigned short* __restrict__ pwB,
                             const float* __restrict__ pb,
                             float* __restrict__ out) {
    __shared__ float mws[7 * KK];        // 4116 B
    __shared__ float dirs[NDIR][3];      //  588 B
    __shared__ float par_s[GG][8];       //  512 B
    __shared__ float der_s[GG][5];       //  320 B
    // union: phase A strip [7][112][4] = 3136 fl (packed) / [3][7][112] (planar);
    // phase B samp[147][17] = 2499 fl.
    __shared__ __align__(16) float buf[3136];   // total ~18 KB

    const int t   = threadIdx.x;
    const int blk = blockIdx.x;
    const int b   = blk >> 6;
    const int rem = blk & 63;
    const int hp  = rem >> 1;
    const int wp0 = (rem & 1) * GG;
    const size_t m0 = (size_t)blk * GG;
    const int row0 = hp * PP;
    const int col0 = wp0 * PP;

    // ---- init: metric weights + direction table
    for (int i = t; i < 7 * KK; i += TB) mws[i] = mw[i];
    if (t >= 64 && t < 64 + NDIR) {
        int n = t - 64;
        float u0, u1, s;
        if (n == 0)      { u0 = 1.0f; u1 = 0.0f; s = 0.0f; }
        else if (n < 9)  { float th = (float)(n - 1)  * 0.78539816339744831f; u0 = cosf(th); u1 = sinf(th); s = 0.33333334f; }
        else if (n < 25) { float th = (float)(n - 9)  * 0.39269908169872414f; u0 = cosf(th); u1 = sinf(th); s = 0.66666669f; }
        else             { float th = (float)(n - 25) * 0.26179938779914941f; u0 = cosf(th); u1 = sinf(th); s = 1.0f; }
        dirs[n][0] = u0; dirs[n][1] = u1; dirs[n][2] = s;
    }

    // ---- stage the block's strip into LDS (coalesced)
    const size_t pbase = (size_t)b * (HH * WW);
    if (PACKED) {
        for (int item = t; item < 7 * NPX; item += TB) {
            int i = item / NPX, px = item - i * NPX;
            f32x4 v = *(const f32x4*)(xp + (pbase + (size_t)(row0 + i) * WW + col0 + px) * 4);
            *(f32x4*)&buf[item * 4] = v;   // xs[i][px][c]
        }
    } else {
        for (int item = t; item < CIN * 7 * NPX; item += TB) {
            int c = item / (7 * NPX), r2 = item - c * (7 * NPX);
            int i = r2 / NPX, px = r2 - i * NPX;
            buf[item] = x[(size_t)b * (CIN * HH * WW) + (size_t)c * (HH * WW)
                          + (size_t)(row0 + i) * WW + col0 + px];
        }
    }
    __syncthreads();

    // ---- metric conv (r2-proven): 112 dots of length 147, low reg pressure
    if (t < 112) {
        int prm = t >> 4, g = t & 15;
        float acc = mb[prm];
        const float* wrow = &mws[prm * KK];
        if (PACKED) {
            #pragma unroll 1
            for (int c = 0; c < CIN; ++c) {
                #pragma unroll 1
                for (int i = 0; i < 7; ++i) {
                    const float* bp = &buf[(i * NPX + g * 7) * 4 + c];
                    const float* wr = &wrow[c * 49 + i * 7];
                    #pragma unroll
                    for (int j = 0; j < 7; ++j)
                        acc = fmaf(bp[j * 4], wr[j], acc);
                }
            }
        } else {
            #pragma unroll 1
            for (int c = 0; c < CIN; ++c) {
                #pragma unroll 1
                for (int i = 0; i < 7; ++i) {
                    const float* bp = &buf[(c * 7 + i) * NPX + g * 7];
                    const float* wr = &wrow[c * 49 + i * 7];
                    #pragma unroll
                    for (int j = 0; j < 7; ++j)
                        acc = fmaf(bp[j], wr[j], acc);
                }
            }
        }
        par_s[g][prm] = acc;
    }
    __syncthreads();

    // ---- derived quantities (proven math)
    if (t < GG) {
        float a0 = par_s[t][0], a1 = par_s[t][1], a2 = par_s[t][2], a3 = par_s[t][3];
        float a4 = par_s[t][4], a5 = par_s[t][5], a6 = par_s[t][6];
        float nrm = sqrtf(a0 * a0 + a1 * a1);
        float inv = 1.0f / fmaxf(nrm, 1e-12f);
        float v0 = a0 * inv, v1 = a1 * inv;
        float e0 = 2.0f * sigmoidf_(a2);
        float e1 = 2.0f * sigmoidf_(a3);
        float sc = 0.5f + 1.5f * sigmoidf_(a4);
        e0 *= sc; e1 *= sc;
        float wn  = sqrtf(a5 * a5 + a6 * a6);
        float wsc = 0.5f * sigmoidf_(wn);
        der_s[t][0] = e0 * v0 * v0 + e1 * v1 * v1;
        der_s[t][1] = (e0 - e1) * v0 * v1;
        der_s[t][2] = e0 * v1 * v1 + e1 * v0 * v0;
        der_s[t][3] = a5 * wsc;
        der_s[t][4] = a6 * wsc;
    }
    __syncthreads();

    // ---- gather into samp[k][17]
    if (PACKED) {
        const float* base = xp + pbase * 4;
        // pair batch: items t and t+256 (always valid; 784 = 3*256+16).
        {
            GInfo A = geom_(t,      row0, col0, dirs, der_s);
            GInfo B = geom_(t + TB, row0, col0, dirs, der_s);
            f32x4 qa0 = *(const f32x4*)(base + (size_t)A.o00 * 4);
            f32x4 qa1 = *(const f32x4*)(base + (size_t)A.o01 * 4);
            f32x4 qa2 = *(const f32x4*)(base + (size_t)A.o10 * 4);
            f32x4 qa3 = *(const f32x4*)(base + (size_t)A.o11 * 4);
            f32x4 qb0 = *(const f32x4*)(base + (size_t)B.o00 * 4);
            f32x4 qb1 = *(const f32x4*)(base + (size_t)B.o01 * 4);
            f32x4 qb2 = *(const f32x4*)(base + (size_t)B.o10 * 4);
            f32x4 qb3 = *(const f32x4*)(base + (size_t)B.o11 * 4);
            __builtin_amdgcn_sched_barrier(0);   // pin 8 loads in flight
            #pragma unroll
            for (int c = 0; c < CIN; ++c)
                buf[(c * NDIR + A.n) * SSTR + A.g] =
                    qa0[c] * A.c00 + qa1[c] * A.c01 + qa2[c] * A.c10 + qa3[c] * A.c11;
            #pragma unroll
            for (int c = 0; c < CIN; ++c)
                buf[(c * NDIR + B.n) * SSTR + B.g] =
                    qb0[c] * B.c00 + qb1[c] * B.c01 + qb2[c] * B.c10 + qb3[c] * B.c11;
        }
        // single: item t+512 (always valid: max 767 < 784)
        {
            GInfo C = geom_(t + 2 * TB, row0, col0, dirs, der_s);
            f32x4 q0 = *(const f32x4*)(base + (size_t)C.o00 * 4);
            f32x4 q1 = *(const f32x4*)(base + (size_t)C.o01 * 4);
            f32x4 q2 = *(const f32x4*)(base + (size_t)C.o10 * 4);
            f32x4 q3 = *(const f32x4*)(base + (size_t)C.o11 * 4);
            #pragma unroll
            for (int c = 0; c < CIN; ++c)
                buf[(c * NDIR + C.n) * SSTR + C.g] =
                    q0[c] * C.c00 + q1[c] * C.c01 + q2[c] * C.c10 + q3[c] * C.c11;
        }
        // tail: items 768..783 (t < 16)
        if (t < GG * NDIR - 3 * TB) {
            GInfo D = geom_(t + 3 * TB, row0, col0, dirs, der_s);
            f32x4 q0 = *(const f32x4*)(base + (size_t)D.o00 * 4);
            f32x4 q1 = *(const f32x4*)(base + (size_t)D.o01 * 4);
            f32x4 q2 = *(const f32x4*)(base + (size_t)D.o10 * 4);
            f32x4 q3 = *(const f32x4*)(base + (size_t)D.o11 * 4);
            #pragma unroll
            for (int c = 0; c < CIN; ++c)
                buf[(c * NDIR + D.n) * SSTR + D.g] =
                    q0[c] * D.c00 + q1[c] * D.c01 + q2[c] * D.c10 + q3[c] * D.c11;
        }
    } else {
        const float* xb = x + (size_t)b * (CIN * HH * WW);
        for (int item = t; item < GG * NDIR; item += TB) {
            GInfo A = geom_(item, row0, col0, dirs, der_s);
            #pragma unroll
            for (int c = 0; c < CIN; ++c) {
                const float* xc = xb + c * (HH * WW);
                buf[(c * NDIR + A.n) * SSTR + A.g] =
                    xc[A.o00] * A.c00 + xc[A.o01] * A.c01 +
                    xc[A.o10] * A.c10 + xc[A.o11] * A.c11;
            }
        }
    }
    __syncthreads();

    // ---- MFMA projection GEMM, operand-swapped (r3/r4/r6 verified): A = pw
    // rows (M=e), B = samp (N=m). Lane owns 4 consecutive e of one output row
    // -> 6x global_store_dwordx4, vectorized bias.
    const int lane = t & 63;
    const int wv   = t >> 6;           // 0..3; wave handles 6 E-tiles
    const int nrow = lane & 15;        // m within block
    const int hi   = lane >> 4;        // k-chunk / e-subrow

    bf16x8 sfr[5];
    #pragma unroll
    for (int ks = 0; ks < 5; ++ks) {
        #pragma unroll
        for (int j = 0; j < 8; ++j) {
            int k = ks * 32 + hi * 8 + j;
            float v = (k < KK) ? buf[k * SSTR + nrow] : 0.0f;
            sfr[ks][j] = (__bf16)v;
        }
    }

    float* orow = out + (m0 + nrow) * EE;
    #pragma unroll
    for (int q = 0; q < 6; ++q) {
        int tile = wv * 6 + q;
        int erow = tile * 16 + nrow;
        const unsigned short* arow = pwB + (size_t)erow * KPAD + hi * 8;
        f32x4 acc = {0.0f, 0.0f, 0.0f, 0.0f};
        #pragma unroll
        for (int ks = 0; ks < 5; ++ks) {
            bf16x8 afr = *(const bf16x8*)&arow[ks * 32];
            acc = __builtin_amdgcn_mfma_f32_16x16x32_bf16(afr, sfr[ks], acc, 0, 0, 0);
        }
        int e0 = tile * 16 + hi * 4;
        f32x4 b4 = *(const f32x4*)&pb[e0];
        f32x4 o = acc + b4;
        *(f32x4*)&orow[e0] = o;
    }
}

extern "C" void kernel_launch(void* const* d_in, const int* in_sizes, int n_in,
                              void* d_out, int out_size, void* d_ws, size_t ws_size,
                              hipStream_t stream) {
    const float* x  = (const float*)d_in[0];
    const float* mw = (const float*)d_in[1];
    const float* mb = (const float*)d_in[2];
    const float* pw = (const float*)d_in[3];
    const float* pb = (const float*)d_in[4];
    float* out = (float*)d_out;

    unsigned short* pwB = (unsigned short*)d_ws;                       // 120 KB (128 KB slot)
    float* xp = (float*)((char*)d_ws + (size_t)(1 << 17));             // packed NHW4 image

    const int B = in_sizes[0] / (CIN * HH * WW);   // 64
    const int npix = B * HH * WW;
    const int npix4 = npix / 4;
    const size_t need = (size_t)(1 << 17) + (size_t)npix * 4 * sizeof(float);
    const bool packed = ws_size >= need;

    if (packed) {
        int grid = (npix4 > EE * KPAD ? npix4 : EE * KPAD);
        pack_kernel<<<(grid + 255) / 256, 256, 0, stream>>>(x, pw, xp, pwB, npix4);
        fused_kernel<true><<<B * 64, TB, 0, stream>>>(x, xp, mw, mb, pwB, pb, out);
    } else {
        pack_kernel<<<(EE * KPAD + 255) / 256, 256, 0, stream>>>(x, pw, xp, pwB, 0);
        fused_kernel<false><<<B * 64, TB, 0, stream>>>(x, xp, mw, mb, pwB, pb, out);
    }
}

// Round 10
// 196.533 us; speedup vs baseline: 1.0933x; 1.0713x over previous
//
#include <hip/hip_runtime.h>
#include <math.h>

#define PP   7
#define NDIR 49
#define CIN  3
#define KK   147      // CIN * 49
#define KPAD 160      // bf16 weight row stride: 5 k-steps of 32, zero-padded tail
#define EE   384
#define HH   224
#define WW   224
#define GG   16       // patches per block
#define TB   256
#define SSTR 17       // samp LDS row stride (+1 pad: conflict-free GEMM reads)
#define NPX  112      // GG*PP pixel columns per block strip

typedef __attribute__((ext_vector_type(8))) __bf16 bf16x8;
typedef __attribute__((ext_vector_type(4))) float  f32x4;

__device__ __forceinline__ float sigmoidf_(float v) {
    return 1.0f / (1.0f + expf(-v));
}

// ---- K0 (packed path): one block per 7x112 strip. Strips exactly tile the
// image (64 images x 64 strips = 4096 blocks), so this kernel does the FULL
// NCHW->NHW4 repack AND the metric conv + derive for its 16 patches — the conv
// VALU hides under the repack's streaming BW, and the 80 derived floats ride in
// the (otherwise zero) 4th lane of the strip's row-0 quads. This removes the
// stage/conv/derive phases (and 2 barriers) from the latency-critical fused
// kernel. pwB bf16 packing is folded in (grid covers 61440 items easily).
__launch_bounds__(TB, 6)
__global__ void pack_strip_kernel(const float* __restrict__ x,
                                  const float* __restrict__ pw,
                                  const float* __restrict__ mw,
                                  const float* __restrict__ mb,
                                  float* __restrict__ xp,
                                  unsigned short* __restrict__ pwB) {
    __shared__ float mws[7 * KK];                    // 4116 B
    __shared__ float par_s[GG][8];                   //  512 B
    __shared__ float der_s[GG][5];                   //  320 B
    __shared__ __align__(16) float buf[CIN * 7 * NPX];  // 9408 B  [c][i][px]

    const int t   = threadIdx.x;
    const int blk = blockIdx.x;

    // pwB packing (independent, guarded)
    int gidx = blk * TB + t;
    if (gidx < EE * KPAD) {
        int e = gidx / KPAD, k = gidx - e * KPAD;
        float v = (k < KK) ? pw[e * KK + k] : 0.0f;
        __bf16 h = (__bf16)v;
        pwB[gidx] = *(unsigned short*)&h;
    }

    const int b   = blk >> 6;
    const int rem = blk & 63;
    const int hp  = rem >> 1;
    const int wp0 = (rem & 1) * GG;
    const int row0 = hp * PP;
    const int col0 = wp0 * PP;
    const float* xb = x + (size_t)b * (CIN * HH * WW);

    // metric weights + strip (planar, coalesced dwordx4: 588 quads)
    for (int i = t; i < 7 * KK; i += TB) mws[i] = mw[i];
    for (int qi = t; qi < 588; qi += TB) {
        int c = qi / 196, r = qi - c * 196, i = r / 28, j = r - i * 28;
        f32x4 v = *(const f32x4*)(xb + (size_t)c * (HH * WW)
                                  + (size_t)(row0 + i) * WW + col0 + j * 4);
        *(f32x4*)&buf[(c * 7 + i) * NPX + j * 4] = v;
    }
    __syncthreads();

    // conv: 112 dots of length 147, 3 per-channel chains (r2-proven math)
    if (t < 112) {
        int prm = t >> 4, g = t & 15;
        const float* wrow = &mws[prm * KK];
        float acc0 = 0.0f, acc1 = 0.0f, acc2 = 0.0f;
        #pragma unroll 1
        for (int i = 0; i < 7; ++i) {
            const float* b0 = &buf[(0 * 7 + i) * NPX + g * 7];
            const float* b1 = &buf[(1 * 7 + i) * NPX + g * 7];
            const float* b2 = &buf[(2 * 7 + i) * NPX + g * 7];
            #pragma unroll
            for (int j = 0; j < 7; ++j) {
                acc0 = fmaf(b0[j], wrow[i * 7 + j], acc0);
                acc1 = fmaf(b1[j], wrow[49 + i * 7 + j], acc1);
                acc2 = fmaf(b2[j], wrow[98 + i * 7 + j], acc2);
            }
        }
        par_s[g][prm] = mb[prm] + acc0 + acc1 + acc2;
    }
    __syncthreads();

    // derive (proven math)
    if (t < GG) {
        float a0 = par_s[t][0], a1 = par_s[t][1], a2 = par_s[t][2], a3 = par_s[t][3];
        float a4 = par_s[t][4], a5 = par_s[t][5], a6 = par_s[t][6];
        float nrm = sqrtf(a0 * a0 + a1 * a1);
        float inv = 1.0f / fmaxf(nrm, 1e-12f);
        float v0 = a0 * inv, v1 = a1 * inv;
        float e0 = 2.0f * sigmoidf_(a2);
        float e1 = 2.0f * sigmoidf_(a3);
        float sc = 0.5f + 1.5f * sigmoidf_(a4);
        e0 *= sc; e1 *= sc;
        float wn  = sqrtf(a5 * a5 + a6 * a6);
        float wsc = 0.5f * sigmoidf_(wn);
        der_s[t][0] = e0 * v0 * v0 + e1 * v1 * v1;
        der_s[t][1] = (e0 - e1) * v0 * v1;
        der_s[t][2] = e0 * v1 * v1 + e1 * v0 * v0;
        der_s[t][3] = a5 * wsc;
        der_s[t][4] = a6 * wsc;
    }
    __syncthreads();

    // write packed quads; der stashed in w of row-0 quads px<80 (w is never
    // read by any gather interp — only c<3 components are used)
    const size_t pbase = (size_t)b * (HH * WW);
    for (int q = t; q < 7 * NPX; q += TB) {
        int i = q / NPX, px = q - i * NPX;
        float w = 0.0f;
        if (i == 0 && px < 80) { int g5 = px / 5; w = der_s[g5][px - g5 * 5]; }
        f32x4 v = { buf[(0 * 7 + i) * NPX + px],
                    buf[(1 * 7 + i) * NPX + px],
                    buf[(2 * 7 + i) * NPX + px], w };
        *(f32x4*)(xp + (pbase + (size_t)(row0 + i) * WW + col0 + px) * 4) = v;
    }
}

// ---- K1 (packed path): gather + GEMM ONLY. r2's exact proven gather loop
// (r4/r8/r9 lesson: every scheduling/structure deviation lost) with the front
// phases moved to pack_strip. Two barriers total.
__launch_bounds__(TB, 8)
__global__ void fused_kernel(const float* __restrict__ xp,
                             const unsigned short* __restrict__ pwB,
                             const float* __restrict__ pb,
                             float* __restrict__ out) {
    __shared__ float dirs[NDIR][3];                  //  588 B
    __shared__ float der_s[GG][5];                   //  320 B
    __shared__ __align__(16) float buf[KK * SSTR];   // 9996 B -> ~11 KB total

    const int t   = threadIdx.x;
    const int blk = blockIdx.x;
    const int b   = blk >> 6;
    const int rem = blk & 63;
    const int hp  = rem >> 1;
    const int wp0 = (rem & 1) * GG;
    const size_t m0 = (size_t)blk * GG;
    const int row0 = hp * PP;
    const int col0 = wp0 * PP;
    const size_t pbase = (size_t)b * (HH * WW);

    // dirs table + der load (from the w-components pack_strip stashed)
    if (t >= 64 && t < 64 + NDIR) {
        int n = t - 64;
        float u0, u1, s;
        if (n == 0)      { u0 = 1.0f; u1 = 0.0f; s = 0.0f; }
        else if (n < 9)  { float th = (float)(n - 1)  * 0.78539816339744831f; u0 = cosf(th); u1 = sinf(th); s = 0.33333334f; }
        else if (n < 25) { float th = (float)(n - 9)  * 0.39269908169872414f; u0 = cosf(th); u1 = sinf(th); s = 0.66666669f; }
        else             { float th = (float)(n - 25) * 0.26179938779914941f; u0 = cosf(th); u1 = sinf(th); s = 1.0f; }
        dirs[n][0] = u0; dirs[n][1] = u1; dirs[n][2] = s;
    }
    if (t < 80) {
        int g5 = t / 5;
        der_s[g5][t - g5 * 5] = xp[(pbase + (size_t)row0 * WW + col0 + t) * 4 + 3];
    }
    __syncthreads();

    // ---- gather into samp[k][17] — r2's exact proven loop
    for (int item = t; item < GG * NDIR; item += TB) {
        int g = item / NDIR;
        int n = item - g * NDIR;
        float u0 = dirs[n][0], u1 = dirs[n][1], s = dirs[n][2];
        float M00 = der_s[g][0], M01 = der_s[g][1], M11 = der_s[g][2];
        float w0 = der_s[g][3], w1 = der_s[g][4];
        float quad  = u0 * u0 * M00 + 2.0f * u0 * u1 * M01 + u1 * u1 * M11;
        float drift = w0 * u0 + w1 * u1;
        float F = sqrtf(quad + 1e-6f) + drift;
        float r = s / (F + 1e-6f);
        float py = (float)(row0 + 3) + u1 * r;
        float px = (float)(col0 + g * PP + 3) + u0 * r;
        float y0f = floorf(py), x0f = floorf(px);
        float y1f = y0f + 1.0f, x1f = x0f + 1.0f;
        float wy = py - y0f, wx = px - x0f;
        float c00 = (1.0f - wy) * (1.0f - wx);
        float c01 = (1.0f - wy) * wx;
        float c10 = wy * (1.0f - wx);
        float c11 = wy * wx;
        bool vy0 = (y0f >= 0.0f) && (y0f <= (float)(HH - 1));
        bool vy1 = (y1f >= 0.0f) && (y1f <= (float)(HH - 1));
        bool vx0 = (x0f >= 0.0f) && (x0f <= (float)(WW - 1));
        bool vx1 = (x1f >= 0.0f) && (x1f <= (float)(WW - 1));
        c00 *= (vy0 && vx0) ? 1.0f : 0.0f;
        c01 *= (vy0 && vx1) ? 1.0f : 0.0f;
        c10 *= (vy1 && vx0) ? 1.0f : 0.0f;
        c11 *= (vy1 && vx1) ? 1.0f : 0.0f;
        int iy0 = (int)fminf(fmaxf(y0f, 0.0f), (float)(HH - 1));
        int iy1 = (int)fminf(fmaxf(y1f, 0.0f), (float)(HH - 1));
        int ix0 = (int)fminf(fmaxf(x0f, 0.0f), (float)(WW - 1));
        int ix1 = (int)fminf(fmaxf(x1f, 0.0f), (float)(WW - 1));
        f32x4 q00 = *(const f32x4*)(xp + (pbase + (size_t)(iy0 * WW + ix0)) * 4);
        f32x4 q01 = *(const f32x4*)(xp + (pbase + (size_t)(iy0 * WW + ix1)) * 4);
        f32x4 q10 = *(const f32x4*)(xp + (pbase + (size_t)(iy1 * WW + ix0)) * 4);
        f32x4 q11 = *(const f32x4*)(xp + (pbase + (size_t)(iy1 * WW + ix1)) * 4);
        #pragma unroll
        for (int c = 0; c < CIN; ++c) {
            buf[(c * NDIR + n) * SSTR + g] =
                q00[c] * c00 + q01[c] * c01 + q10[c] * c10 + q11[c] * c11;
        }
    }
    __syncthreads();

    // ---- MFMA projection GEMM, operand-swapped (r3/r9 verified): A = pw rows
    // (M=e), B = samp (N=m). Lane owns 4 consecutive e -> dwordx4 stores.
    const int lane = t & 63;
    const int wv   = t >> 6;
    const int nrow = lane & 15;
    const int hi   = lane >> 4;

    bf16x8 sfr[5];
    #pragma unroll
    for (int ks = 0; ks < 5; ++ks) {
        #pragma unroll
        for (int j = 0; j < 8; ++j) {
            int k = ks * 32 + hi * 8 + j;
            float v = (k < KK) ? buf[k * SSTR + nrow] : 0.0f;
            sfr[ks][j] = (__bf16)v;
        }
    }

    float* orow = out + (m0 + nrow) * EE;
    #pragma unroll
    for (int q = 0; q < 6; ++q) {
        int tile = wv * 6 + q;
        int erow = tile * 16 + nrow;
        const unsigned short* arow = pwB + (size_t)erow * KPAD + hi * 8;
        f32x4 acc = {0.0f, 0.0f, 0.0f, 0.0f};
        #pragma unroll
        for (int ks = 0; ks < 5; ++ks) {
            bf16x8 afr = *(const bf16x8*)&arow[ks * 32];
            acc = __builtin_amdgcn_mfma_f32_16x16x32_bf16(afr, sfr[ks], acc, 0, 0, 0);
        }
        int e0 = tile * 16 + hi * 4;
        f32x4 b4 = *(const f32x4*)&pb[e0];
        f32x4 o = acc + b4;
        *(f32x4*)&orow[e0] = o;
    }
}

// ---- fallback path (workspace too small for packed image): proven planar
// all-in-one kernel (r3/r6 structure) + minimal pw pack.
__global__ void pack_pw_kernel(const float* __restrict__ pw, unsigned short* __restrict__ pwB) {
    int idx = blockIdx.x * blockDim.x + threadIdx.x;
    if (idx < EE * KPAD) {
        int e = idx / KPAD;
        int k = idx - e * KPAD;
        float v = (k < KK) ? pw[e * KK + k] : 0.0f;
        __bf16 h = (__bf16)v;
        pwB[idx] = *(unsigned short*)&h;
    }
}

__launch_bounds__(TB, 6)
__global__ void fused_planar_kernel(const float* __restrict__ x,
                                    const float* __restrict__ mw,
                                    const float* __restrict__ mb,
                                    const unsigned short* __restrict__ pwB,
                                    const float* __restrict__ pb,
                                    float* __restrict__ out) {
    __shared__ float mws[7 * KK];
    __shared__ float dirs[NDIR][3];
    __shared__ float par_s[GG][8];
    __shared__ float der_s[GG][5];
    __shared__ __align__(16) float buf[2512];

    const int t   = threadIdx.x;
    const int blk = blockIdx.x;
    const int b   = blk >> 6;
    const int rem = blk & 63;
    const int hp  = rem >> 1;
    const int wp0 = (rem & 1) * GG;
    const size_t m0 = (size_t)blk * GG;
    const int row0 = hp * PP;
    const int col0 = wp0 * PP;
    const float* xb = x + (size_t)b * (CIN * HH * WW);

    for (int i = t; i < 7 * KK; i += TB) mws[i] = mw[i];
    if (t >= 64 && t < 64 + NDIR) {
        int n = t - 64;
        float u0, u1, s;
        if (n == 0)      { u0 = 1.0f; u1 = 0.0f; s = 0.0f; }
        else if (n < 9)  { float th = (float)(n - 1)  * 0.78539816339744831f; u0 = cosf(th); u1 = sinf(th); s = 0.33333334f; }
        else if (n < 25) { float th = (float)(n - 9)  * 0.39269908169872414f; u0 = cosf(th); u1 = sinf(th); s = 0.66666669f; }
        else             { float th = (float)(n - 25) * 0.26179938779914941f; u0 = cosf(th); u1 = sinf(th); s = 1.0f; }
        dirs[n][0] = u0; dirs[n][1] = u1; dirs[n][2] = s;
    }
    for (int item = t; item < CIN * 7 * NPX; item += TB) {
        int c = item / (7 * NPX), r2 = item - c * (7 * NPX);
        int i = r2 / NPX, px = r2 - i * NPX;
        buf[item] = xb[(size_t)c * (HH * WW) + (size_t)(row0 + i) * WW + col0 + px];
    }
    __syncthreads();
    if (t < 112) {
        int prm = t >> 4, g = t & 15;
        const float* wrow = &mws[prm * KK];
        float acc0 = 0.0f, acc1 = 0.0f, acc2 = 0.0f;
        #pragma unroll 1
        for (int i = 0; i < 7; ++i) {
            const float* b0 = &buf[(0 * 7 + i) * NPX + g * 7];
            const float* b1 = &buf[(1 * 7 + i) * NPX + g * 7];
            const float* b2 = &buf[(2 * 7 + i) * NPX + g * 7];
            #pragma unroll
            for (int j = 0; j < 7; ++j) {
                acc0 = fmaf(b0[j], wrow[i * 7 + j], acc0);
                acc1 = fmaf(b1[j], wrow[49 + i * 7 + j], acc1);
                acc2 = fmaf(b2[j], wrow[98 + i * 7 + j], acc2);
            }
        }
        par_s[g][prm] = mb[prm] + acc0 + acc1 + acc2;
    }
    __syncthreads();
    if (t < GG) {
        float a0 = par_s[t][0], a1 = par_s[t][1], a2 = par_s[t][2], a3 = par_s[t][3];
        float a4 = par_s[t][4], a5 = par_s[t][5], a6 = par_s[t][6];
        float nrm = sqrtf(a0 * a0 + a1 * a1);
        float inv = 1.0f / fmaxf(nrm, 1e-12f);
        float v0 = a0 * inv, v1 = a1 * inv;
        float e0 = 2.0f * sigmoidf_(a2);
        float e1 = 2.0f * sigmoidf_(a3);
        float sc = 0.5f + 1.5f * sigmoidf_(a4);
        e0 *= sc; e1 *= sc;
        float wn  = sqrtf(a5 * a5 + a6 * a6);
        float wsc = 0.5f * sigmoidf_(wn);
        der_s[t][0] = e0 * v0 * v0 + e1 * v1 * v1;
        der_s[t][1] = (e0 - e1) * v0 * v1;
        der_s[t][2] = e0 * v1 * v1 + e1 * v0 * v0;
        der_s[t][3] = a5 * wsc;
        der_s[t][4] = a6 * wsc;
    }
    __syncthreads();
    for (int item = t; item < GG * NDIR; item += TB) {
        int g = item / NDIR;
        int n = item - g * NDIR;
        float u0 = dirs[n][0], u1 = dirs[n][1], s = dirs[n][2];
        float M00 = der_s[g][0], M01 = der_s[g][1], M11 = der_s[g][2];
        float w0 = der_s[g][3], w1 = der_s[g][4];
        float quad  = u0 * u0 * M00 + 2.0f * u0 * u1 * M01 + u1 * u1 * M11;
        float drift = w0 * u0 + w1 * u1;
        float F = sqrtf(quad + 1e-6f) + drift;
        float r = s / (F + 1e-6f);
        float py = (float)(row0 + 3) + u1 * r;
        float px = (float)(col0 + g * PP + 3) + u0 * r;
        float y0f = floorf(py), x0f = floorf(px);
        float y1f = y0f + 1.0f, x1f = x0f + 1.0f;
        float wy = py - y0f, wx = px - x0f;
        float c00 = (1.0f - wy) * (1.0f - wx);
        float c01 = (1.0f - wy) * wx;
        float c10 = wy * (1.0f - wx);
        float c11 = wy * wx;
        bool vy0 = (y0f >= 0.0f) && (y0f <= (float)(HH - 1));
        bool vy1 = (y1f >= 0.0f) && (y1f <= (float)(HH - 1));
        bool vx0 = (x0f >= 0.0f) && (x0f <= (float)(WW - 1));
        bool vx1 = (x1f >= 0.0f) && (x1f <= (float)(WW - 1));
        c00 *= (vy0 && vx0) ? 1.0f : 0.0f;
        c01 *= (vy0 && vx1) ? 1.0f : 0.0f;
        c10 *= (vy1 && vx0) ? 1.0f : 0.0f;
        c11 *= (vy1 && vx1) ? 1.0f : 0.0f;
        int iy0 = (int)fminf(fmaxf(y0f, 0.0f), (float)(HH - 1));
        int iy1 = (int)fminf(fmaxf(y1f, 0.0f), (float)(HH - 1));
        int ix0 = (int)fminf(fmaxf(x0f, 0.0f), (float)(WW - 1));
        int ix1 = (int)fminf(fmaxf(x1f, 0.0f), (float)(WW - 1));
        int o00 = iy0 * WW + ix0, o01 = iy0 * WW + ix1;
        int o10 = iy1 * WW + ix0, o11 = iy1 * WW + ix1;
        #pragma unroll
        for (int c = 0; c < CIN; ++c) {
            const float* xc = xb + c * (HH * WW);
            buf[(c * NDIR + n) * SSTR + g] =
                xc[o00] * c00 + xc[o01] * c01 + xc[o10] * c10 + xc[o11] * c11;
        }
    }
    __syncthreads();
    const int lane = t & 63;
    const int wv   = t >> 6;
    const int nrow = lane & 15;
    const int hi   = lane >> 4;
    bf16x8 sfr[5];
    #pragma unroll
    for (int ks = 0; ks < 5; ++ks) {
        #pragma unroll
        for (int j = 0; j < 8; ++j) {
            int k = ks * 32 + hi * 8 + j;
            float v = (k < KK) ? buf[k * SSTR + nrow] : 0.0f;
            sfr[ks][j] = (__bf16)v;
        }
    }
    float* orow = out + (m0 + nrow) * EE;
    #pragma unroll
    for (int q = 0; q < 6; ++q) {
        int tile = wv * 6 + q;
        int erow = tile * 16 + nrow;
        const unsigned short* arow = pwB + (size_t)erow * KPAD + hi * 8;
        f32x4 acc = {0.0f, 0.0f, 0.0f, 0.0f};
        #pragma unroll
        for (int ks = 0; ks < 5; ++ks) {
            bf16x8 afr = *(const bf16x8*)&arow[ks * 32];
            acc = __builtin_amdgcn_mfma_f32_16x16x32_bf16(afr, sfr[ks], acc, 0, 0, 0);
        }
        int e0 = tile * 16 + hi * 4;
        f32x4 b4 = *(const f32x4*)&pb[e0];
        f32x4 o = acc + b4;
        *(f32x4*)&orow[e0] = o;
    }
}

extern "C" void kernel_launch(void* const* d_in, const int* in_sizes, int n_in,
                              void* d_out, int out_size, void* d_ws, size_t ws_size,
                              hipStream_t stream) {
    const float* x  = (const float*)d_in[0];
    const float* mw = (const float*)d_in[1];
    const float* mb = (const float*)d_in[2];
    const float* pw = (const float*)d_in[3];
    const float* pb = (const float*)d_in[4];
    float* out = (float*)d_out;

    unsigned short* pwB = (unsigned short*)d_ws;                       // 120 KB (128 KB slot)
    float* xp = (float*)((char*)d_ws + (size_t)(1 << 17));             // packed NHW4 image

    const int B = in_sizes[0] / (CIN * HH * WW);   // 64
    const int npix = B * HH * WW;
    const size_t need = (size_t)(1 << 17) + (size_t)npix * 4 * sizeof(float);
    const bool packed = ws_size >= need;

    if (packed) {
        pack_strip_kernel<<<B * 64, TB, 0, stream>>>(x, pw, mw, mb, xp, pwB);
        fused_kernel<<<B * 64, TB, 0, stream>>>(xp, pwB, pb, out);
    } else {
        pack_pw_kernel<<<(EE * KPAD + 255) / 256, 256, 0, stream>>>(pw, pwB);
        fused_planar_kernel<<<B * 64, TB, 0, stream>>>(x, mw, mb, pwB, pb, out);
    }
}